// Round 7
// baseline (251.134 us; speedup 1.0000x reference)
//
#include <hip/hip_runtime.h>
#include <hip/hip_fp16.h>

#define Bc   2
#define Tc   2048
#define DIMc 1024
#define Hc   16
#define KVHc 4
#define HDc  64
#define Mc   4096   // B*T

typedef unsigned short u16;
typedef __attribute__((ext_vector_type(8))) short short8;
typedef __attribute__((ext_vector_type(8))) __bf16 bf16x8;
typedef __attribute__((ext_vector_type(2))) __bf16 bf16x2;
typedef __attribute__((ext_vector_type(4))) float f32x4;
typedef __attribute__((ext_vector_type(4))) unsigned short u16x4;

typedef const __attribute__((address_space(1))) void* gas_t;
typedef __attribute__((address_space(3))) void* las_t;

#define L2E 1.4426950408889634f
#define L2B 0.41524101186092035f   // log2(10000)/32

__device__ inline float bf2f(u16 u) {
    unsigned int x = ((unsigned int)u) << 16;
    return __builtin_bit_cast(float, x);
}
__device__ inline u16 f2bf(float f) {  // RNE
    unsigned int x = __builtin_bit_cast(unsigned int, f);
    x += 0x7fffu + ((x >> 16) & 1u);
    return (u16)(x >> 16);
}
// packed f32x2 -> bf16x2 (single HW inst when available; RNE either way)
__device__ inline unsigned int pkbf(float a, float b) {
#if __has_builtin(__builtin_amdgcn_cvt_pk_bf16_f32)
    bf16x2 r = __builtin_amdgcn_cvt_pk_bf16_f32(a, b);
    return __builtin_bit_cast(unsigned int, r);
#else
    return (unsigned int)f2bf(a) | ((unsigned int)f2bf(b) << 16);
#endif
}
__device__ inline u16x4 pk4(float a, float b, float c, float d) {
    uint2 u; u.x = pkbf(a, b); u.y = pkbf(c, d);
    return __builtin_bit_cast(u16x4, u);
}
__device__ inline float fexp2(float x) {
#if __has_builtin(__builtin_amdgcn_exp2f)
    return __builtin_amdgcn_exp2f(x);
#else
    return exp2f(x);
#endif
}
__device__ inline bf16x8 ld8(const u16* p) {
    return __builtin_bit_cast(bf16x8, *(const short8*)p);
}
__device__ inline f32x4 mfma16(bf16x8 a, bf16x8 b, f32x4 c) {
    return __builtin_amdgcn_mfma_f32_16x16x32_bf16(a, b, c, 0, 0, 0);
}
__device__ inline void gl_lds16(const u16* g, u16* l) {
    __builtin_amdgcn_global_load_lds((gas_t)g, (las_t)l, 16, 0, 0);
}

// ---------------------------------------------------------------------------
// prep: blocks [0,4096) = x fp32->bf16 cast; [4096,6656) = int6 RTN fake-quant
// rows with the rank-32 LoRA product FOLDED IN: Weff[n,k] = Wdeq[n,k] +
// sum_r A[k,r]*B[r,n]. This makes projections single GEMMs (no tails, no
// transposes, no xA/yA stages). B-column loads are block-uniform -> scalar.
// ---------------------------------------------------------------------------
__device__ inline float block_sum(float v, volatile float* red) {
    #pragma unroll
    for (int off = 32; off; off >>= 1) v += __shfl_xor(v, off);
    __syncthreads();
    if ((threadIdx.x & 63) == 0) red[threadIdx.x >> 6] = v;
    __syncthreads();
    return red[0] + red[1] + red[2] + red[3];
}
__device__ inline float block_max(float v, volatile float* red) {
    #pragma unroll
    for (int off = 32; off; off >>= 1) v = fmaxf(v, __shfl_xor(v, off));
    __syncthreads();
    if ((threadIdx.x & 63) == 0) red[threadIdx.x >> 6] = v;
    __syncthreads();
    return fmaxf(fmaxf(red[0], red[1]), fmaxf(red[2], red[3]));
}

__global__ __launch_bounds__(256) void prep_kernel(
    const float* __restrict__ x,
    const float* __restrict__ Wq, const float* __restrict__ Wk,
    const float* __restrict__ Wv, const float* __restrict__ Wo,
    const float* __restrict__ qA, const float* __restrict__ kA,
    const float* __restrict__ vA, const float* __restrict__ pA,
    const float* __restrict__ qB, const float* __restrict__ kB,
    const float* __restrict__ vB, const float* __restrict__ pB,
    u16* __restrict__ x_bf,
    u16* __restrict__ Wqkv_b, u16* __restrict__ Wo_b)
{
    __shared__ float red[4];
    const int bx = blockIdx.x;
    const int tid = threadIdx.x;

    if (bx < 4096) {                       // --- x fp32 -> bf16 ---
        const int i = bx * 256 + tid;
        float4 v = ((const float4*)x)[i];
        ((u16x4*)x_bf)[i] = pk4(v.x, v.y, v.z, v.w);
        return;
    }
    // --- int6 RTN fake-quant + LoRA fold, one block per weight row ---
    const int rblk = bx - 4096;
    const float* src; u16* dst; const float* Apt; const float* Bpt;
    int nn, bdim;
    if (rblk < 1024)      { src = Wq + (size_t)rblk * DIMc;          dst = Wqkv_b + (size_t)rblk * DIMc;
                            Apt = qA; Bpt = qB; nn = rblk;        bdim = 1024; }
    else if (rblk < 1280) { src = Wk + (size_t)(rblk - 1024) * DIMc; dst = Wqkv_b + (size_t)rblk * DIMc;
                            Apt = kA; Bpt = kB; nn = rblk - 1024; bdim = 256; }
    else if (rblk < 1536) { src = Wv + (size_t)(rblk - 1280) * DIMc; dst = Wqkv_b + (size_t)rblk * DIMc;
                            Apt = vA; Bpt = vB; nn = rblk - 1280; bdim = 256; }
    else                  { src = Wo + (size_t)(rblk - 1536) * DIMc; dst = Wo_b + (size_t)(rblk - 1536) * DIMc;
                            Apt = pA; Bpt = pB; nn = rblk - 1536; bdim = 1024; }

    float4 fv = ((const float4*)src)[tid];
    float tv[4] = {fv.x, fv.y, fv.z, fv.w};
    float ps = tv[0] + tv[1] + tv[2] + tv[3];
    float pa = fmaxf(fmaxf(fabsf(tv[0]), fabsf(tv[1])),
                     fmaxf(fabsf(tv[2]), fabsf(tv[3])));
    const float sum  = block_sum(ps, red);
    const float amax = block_max(pa, red);
    const float mean = sum * (1.0f / 1024.0f);
    float psq = 0.f;
    #pragma unroll
    for (int j = 0; j < 4; j++) { float d = tv[j] - mean; psq += d * d; }
    const float var  = block_sum(psq, red) * (1.0f / 1024.0f);
    const float row_std    = fmaxf(sqrtf(var), 1e-8f);
    const float row_absmax = fmaxf(amax, 1.0f / 31.0f);
    const float s1 = fmaxf(fmaxf(row_std * 12.85f, row_absmax * (1.0f / 31.0f)) * (1.0f / 31.0f),
                           1.0f / 31.0f);
    const float s2 = fmaxf(row_absmax * (1.0f / 31.0f), 1.0f / 31.0f);
    float pe1 = 0.f, pe2 = 0.f;
    #pragma unroll
    for (int j = 0; j < 4; j++) {
        float q1 = fminf(fmaxf(rintf(tv[j] / s1), -31.f), 31.f);
        float q2 = fminf(fmaxf(rintf(tv[j] / s2), -31.f), 31.f);
        float d1 = q1 * s1 - tv[j], d2 = q2 * s2 - tv[j];
        pe1 += d1 * d1; pe2 += d2 * d2;
    }
    const float e1 = block_sum(pe1, red);
    const float e2 = block_sum(pe2, red);
    const float ss = (e1 < e2) ? s1 : s2;
    const float sh = __half2float(__float2half(ss));

    // LoRA fold: lora[j] = sum_r Apt[(tid*4+j), r] * Bpt[r, nn]
    float Bcol[32];
    #pragma unroll
    for (int r = 0; r < 32; r++) Bcol[r] = Bpt[(size_t)r * bdim + nn];  // uniform
    float lora[4];
    #pragma unroll
    for (int j = 0; j < 4; j++) {
        const float4* ar = (const float4*)(Apt + (size_t)(tid * 4 + j) * 32);
        float acc = 0.f;
        #pragma unroll
        for (int rr = 0; rr < 8; rr++) {
            float4 a4 = ar[rr];
            acc += a4.x * Bcol[rr * 4] + a4.y * Bcol[rr * 4 + 1]
                 + a4.z * Bcol[rr * 4 + 2] + a4.w * Bcol[rr * 4 + 3];
        }
        lora[j] = acc;
    }
    u16x4 outv;
    #pragma unroll
    for (int j = 0; j < 4; j++) {
        float q = fminf(fmaxf(rintf(tv[j] / ss), -31.f), 31.f);
        outv[j] = f2bf(q * sh + lora[j]);
    }
    ((u16x4*)dst)[tid] = outv;
}

// ---------------------------------------------------------------------------
// gemm_tn: C[M,N] = A[M,K] @ B[N,K]^T. Tile 64M x 128N, 4 waves (wave =
// 32M x 64N, acc[2][4]). K=1024, BK=32. Double-buffered global_load_lds
// staging with double-XOR chunk swizzle on the global side.
// mode 0: fp32 store to Cf.
// mode 2: fused QKV epilogue — q cols (<1024): RoPE + gain*0.125*log2e ->
//   qatt (b,h,t,hd); k cols (1024..1279): RoPE -> katt (b,kvh,t,hd);
//   v cols (1280..1535): transpose -> vatt (b,kvh,hd,t).
// ---------------------------------------------------------------------------
__global__ __launch_bounds__(256) void gemm_tn(
    const u16* __restrict__ A, const u16* __restrict__ Bm, int K,
    int mode, float* __restrict__ Cf, int ldc,
    const float* __restrict__ q_gain,
    u16* __restrict__ qatt, u16* __restrict__ katt, u16* __restrict__ vatt)
{
    __shared__ __align__(16) u16 As[2][2048];   // 64 x 32
    __shared__ __align__(16) u16 Bs[2][4096];   // 128 x 32
    const int tid = threadIdx.x;
    const int wave = tid >> 6, lane = tid & 63;
    const int quad = lane >> 4, l16 = lane & 15;
    const int wm = wave >> 1, wn = wave & 1;
    const int tileM = blockIdx.y * 64, tileN = blockIdx.x * 128;

    const u16* Abase = A + (size_t)tileM * K;
    const u16* Bbase = Bm + (size_t)tileN * K;

    auto stage_it = [&](int k0, int buf) {
        {   // A: 256 chunks, 1/thread
            const int g = tid;
            const int r = g >> 2;
            const int cg = (g & 3) ^ (r & 3) ^ ((r >> 2) & 3);
            gl_lds16(Abase + (size_t)r * K + k0 + cg * 8, &As[buf][(size_t)g * 8]);
        }
        #pragma unroll
        for (int i = 0; i < 2; i++) {   // B: 512 chunks, 2/thread
            const int g = i * 256 + tid;
            const int r = g >> 2;
            const int cg = (g & 3) ^ (r & 3) ^ ((r >> 2) & 3);
            gl_lds16(Bbase + (size_t)r * K + k0 + cg * 8, &Bs[buf][(size_t)g * 8]);
        }
    };

    const int niter = K / 32;
    const int slot = quad ^ (l16 & 3) ^ ((l16 >> 2) & 3);
    f32x4 acc[2][4] = {};

    stage_it(0, 0);
    for (int it = 0; it < niter; it++) {
        const int buf = it & 1;
        __syncthreads();
        if (it + 1 < niter) stage_it((it + 1) * 32, buf ^ 1);
        bf16x8 af[2], bfr[4];
        #pragma unroll
        for (int mi = 0; mi < 2; mi++)
            af[mi] = ld8(&As[buf][(wm * 32 + mi * 16 + l16) * 32 + slot * 8]);
        #pragma unroll
        for (int ni = 0; ni < 4; ni++)
            bfr[ni] = ld8(&Bs[buf][(wn * 64 + ni * 16 + l16) * 32 + slot * 8]);
        #pragma unroll
        for (int mi = 0; mi < 2; mi++)
        #pragma unroll
        for (int ni = 0; ni < 4; ni++)
            acc[mi][ni] = mfma16(af[mi], bfr[ni], acc[mi][ni]);
    }

    const int row0 = tileM + wm * 32;
    const int col0 = tileN + wn * 64;
    if (mode == 0) {
        #pragma unroll
        for (int mi = 0; mi < 2; mi++)
        #pragma unroll
        for (int ni = 0; ni < 4; ni++)
        #pragma unroll
        for (int r = 0; r < 4; r++)
            Cf[(size_t)(row0 + mi * 16 + quad * 4 + r) * ldc + col0 + ni * 16 + l16]
                = acc[mi][ni][r];
        return;
    }
    // mode 2: fused qkv epilogue
    const int bb = row0 >> 11;
    const int trow = row0 & (Tc - 1);
    if (col0 < 1024) {                               // ---- q: RoPE, (t,hd) ----
        const int hh = col0 >> 6;
        const float g = q_gain[hh] * (0.125f * L2E);
        u16* qh = qatt + (size_t)(bb * Hc + hh) * Tc * HDc;
        #pragma unroll
        for (int ni = 0; ni < 2; ni++) {
            const int p = ni * 16 + l16;
            const float infr = fexp2(-L2B * (float)p);
            #pragma unroll
            for (int mi = 0; mi < 2; mi++) {
                #pragma unroll
                for (int r = 0; r < 4; r++) {
                    const int t = trow + mi * 16 + quad * 4 + r;
                    float s, c; __sincosf((float)t * infr, &s, &c);
                    const float x1 = acc[mi][ni][r], x2 = acc[mi][ni + 2][r];
                    qh[(size_t)t * HDc + p]      = f2bf((x1 * c + x2 * s) * g);
                    qh[(size_t)t * HDc + p + 32] = f2bf((x2 * c - x1 * s) * g);
                }
            }
        }
    } else if (col0 < 1280) {                        // ---- k: RoPE, (t,hd) ----
        const int kvh = (col0 - 1024) >> 6;
        u16* kh = katt + (size_t)(bb * KVHc + kvh) * Tc * HDc;
        #pragma unroll
        for (int ni = 0; ni < 2; ni++) {
            const int p = ni * 16 + l16;
            const float infr = fexp2(-L2B * (float)p);
            #pragma unroll
            for (int mi = 0; mi < 2; mi++) {
                #pragma unroll
                for (int r = 0; r < 4; r++) {
                    const int t = trow + mi * 16 + quad * 4 + r;
                    float s, c; __sincosf((float)t * infr, &s, &c);
                    const float x1 = acc[mi][ni][r], x2 = acc[mi][ni + 2][r];
                    kh[(size_t)t * HDc + p]      = f2bf(x1 * c + x2 * s);
                    kh[(size_t)t * HDc + p + 32] = f2bf(x2 * c - x1 * s);
                }
            }
        }
    } else {                                         // ---- v: (hd,t) ----
        const int kvh = (col0 - 1280) >> 6;
        u16* vh = vatt + (size_t)(bb * KVHc + kvh) * HDc * Tc;
        #pragma unroll
        for (int ni = 0; ni < 4; ni++) {
            const int hd = ni * 16 + l16;
            #pragma unroll
            for (int mi = 0; mi < 2; mi++) {
                const int t0 = trow + mi * 16 + quad * 4;
                u16x4 ov = pk4(acc[mi][ni][0], acc[mi][ni][1],
                               acc[mi][ni][2], acc[mi][ni][3]);
                *(u16x4*)(vh + (size_t)hd * Tc + t0) = ov;
            }
        }
    }
}

// ---------------------------------------------------------------------------
// Flash attention v6. v4 grid (32 x B*H, 1024 blocks, 4/CU) + balanced qtile
// mapping. NO-MAX online softmax: q pre-scaled by gain*0.125*log2e, scores
// are log2-units and bounded (|s| <~ 5), so p = exp2(s) directly; l is a
// per-lane accumulator reduced once at the end. Zero cross-lane ops and no
// O-rescale in the K-loop. HW exp2 + packed bf16 cvt.
// K/V 64x64 tiles double-buffered in LDS via global_load_lds + XOR swizzle.
// ---------------------------------------------------------------------------
__global__ __launch_bounds__(256) void flash_attn6(
    const u16* __restrict__ qatt, const u16* __restrict__ katt,
    const u16* __restrict__ vatt, const float* __restrict__ head_gate,
    u16* __restrict__ ybf)
{
    __shared__ __align__(16) u16 sm[20480];   // [0,8192)=Kdbuf [8192,16384)=Vdbuf [16384,20480)=P
    const int tid = threadIdx.x;
    const int wv = tid >> 6, lane = tid & 63;
    const int quad = lane >> 4, l16 = lane & 15;
    const int sw = l16 & 7;
    const int bh = blockIdx.y;
    const int b = bh >> 4, h = bh & 15;
    const int kvh = h >> 2;
    const int x = blockIdx.x, s = bh >> 3;
    int qtile;
    if      (s == 0) qtile = x;
    else if (s == 1) qtile = 31 - x;
    else if (s == 2) qtile = (x + 8) & 31;
    else             qtile = 31 - ((x + 8) & 31);
    const int qw = qtile * 64 + wv * 16;
    const int nkt = qtile + 1;

    const u16* qbase = qatt + ((size_t)((b * Hc + h) * Tc + qw + l16)) * HDc;
    const bf16x8 bq0 = ld8(qbase + quad * 8);
    const bf16x8 bq1 = ld8(qbase + 32 + quad * 8);

    const u16* kbase = katt + (size_t)(b * KVHc + kvh) * Tc * HDc;
    const u16* vbase = vatt + (size_t)(b * KVHc + kvh) * HDc * Tc;

    auto stage = [&](int k0, int bb2) {
        #pragma unroll
        for (int i = 0; i < 2; i++) {
            const int g = wv * 128 + i * 64 + lane;
            const int r = g >> 3;
            const int cg = (g & 7) ^ (r & 7);
            gl_lds16(kbase + (size_t)(k0 + r) * HDc + cg * 8,
                     &sm[bb2 * 4096 + wv * 1024 + i * 512]);
            gl_lds16(vbase + (size_t)r * Tc + k0 + cg * 8,
                     &sm[8192 + bb2 * 4096 + wv * 1024 + i * 512]);
        }
    };

    float lsum = 0.f;
    f32x4 o[4] = {};
    u16* pw = &sm[16384 + wv * 1024];

    stage(0, 0);
    for (int kt = 0; kt < nkt; kt++) {
        const int bb2 = kt & 1;
        __syncthreads();
        if (kt + 1 < nkt) stage((kt + 1) * 64, bb2 ^ 1);

        const u16* Kb = &sm[bb2 * 4096];
        const u16* Vb = &sm[8192 + bb2 * 4096];
        f32x4 st[4];
        #pragma unroll
        for (int ft = 0; ft < 4; ft++) {
            const u16* kp = Kb + (ft * 16 + l16) * 64;
            bf16x8 a0 = ld8(kp + ((quad ^ sw) << 3));
            bf16x8 a1 = ld8(kp + (((quad + 4) ^ sw) << 3));
            f32x4 sacc = {};
            sacc = mfma16(a0, bq0, sacc);
            sacc = mfma16(a1, bq1, sacc);
            st[ft] = sacc;
        }
        if (kt == nkt - 1) {                 // diagonal: causal mask
            const int qloc = wv * 16 + l16;
            #pragma unroll
            for (int ft = 0; ft < 4; ft++)
                #pragma unroll
                for (int r = 0; r < 4; r++)
                    if (ft * 16 + quad * 4 + r > qloc) st[ft][r] = -1e30f;
        }
        #pragma unroll
        for (int ft = 0; ft < 4; ft++) {
            const float p0 = fexp2(st[ft][0]);
            const float p1 = fexp2(st[ft][1]);
            const float p2 = fexp2(st[ft][2]);
            const float p3 = fexp2(st[ft][3]);
            lsum += (p0 + p1) + (p2 + p3);
            const int c = (ft << 1) + (quad >> 1);
            u16* pd = &pw[(l16 << 6) + ((c ^ sw) << 3) + ((quad & 1) << 2)];
            uint2 pkv; pkv.x = pkbf(p0, p1); pkv.y = pkbf(p2, p3);
            *(uint2*)pd = pkv;
        }
        const bf16x8 pa0 = ld8(&pw[(l16 << 6) + ((quad ^ sw) << 3)]);
        const bf16x8 pa1 = ld8(&pw[(l16 << 6) + (((quad + 4) ^ sw) << 3)]);
        #pragma unroll
        for (int f = 0; f < 4; f++) {
            const u16* vp = Vb + (f * 16 + l16) * 64;
            bf16x8 v0 = ld8(vp + ((quad ^ sw) << 3));
            bf16x8 v1 = ld8(vp + (((quad + 4) ^ sw) << 3));
            o[f] = mfma16(v0, pa0, o[f]);
            o[f] = mfma16(v1, pa1, o[f]);
        }
    }
    lsum += __shfl_xor(lsum, 16);
    lsum += __shfl_xor(lsum, 32);
    const float inv = head_gate[h] / lsum;
    u16* yb = ybf + ((size_t)(b * Tc + qw + l16)) * DIMc + h * HDc + quad * 4;
    #pragma unroll
    for (int f = 0; f < 4; f++) {
        u16x4 pk = pk4(o[f][0] * inv, o[f][1] * inv,
                       o[f][2] * inv, o[f][3] * inv);
        *(u16x4*)(yb + f * 16) = pk;
    }
}

// ---------------------------------------------------------------------------
extern "C" void kernel_launch(void* const* d_in, const int* in_sizes, int n_in,
                              void* d_out, int out_size, void* d_ws, size_t ws_size,
                              hipStream_t stream) {
    (void)in_sizes; (void)n_in; (void)out_size; (void)ws_size;
    const float* x    = (const float*)d_in[0];
    const float* Wq   = (const float*)d_in[1];
    const float* Wk   = (const float*)d_in[2];
    const float* Wv   = (const float*)d_in[3];
    const float* Wo   = (const float*)d_in[4];
    const float* qA   = (const float*)d_in[5];
    const float* qB   = (const float*)d_in[6];
    const float* kA   = (const float*)d_in[7];
    const float* kB   = (const float*)d_in[8];
    const float* vA   = (const float*)d_in[9];
    const float* vB   = (const float*)d_in[10];
    const float* pA   = (const float*)d_in[11];
    const float* pB   = (const float*)d_in[12];
    const float* q_gain    = (const float*)d_in[13];
    const float* head_gate = (const float*)d_in[14];
    float* out = (float*)d_out;

    char* wsp = (char*)d_ws;
    size_t off = 0;
    auto alloc = [&](size_t bytes) -> void* {
        void* p = wsp + off;
        off = (off + bytes + 255) & ~(size_t)255;
        return p;
    };
    u16* x_bf   = (u16*)alloc((size_t)Mc * DIMc * 2);
    u16* Wqkv_b = (u16*)alloc((size_t)1536 * DIMc * 2);   // LoRA-folded Weff
    u16* Wo_b   = (u16*)alloc((size_t)DIMc * DIMc * 2);   // LoRA-folded Weff
    u16* qatt   = (u16*)alloc((size_t)Mc * DIMc * 2);
    u16* katt   = (u16*)alloc((size_t)Mc * 256 * 2);
    u16* vatt   = (u16*)alloc((size_t)Mc * 256 * 2);
    u16* y_bf   = (u16*)alloc((size_t)Mc * DIMc * 2);

    // 1. cast + quant(+LoRA fold)
    prep_kernel<<<6656, 256, 0, stream>>>(x, Wq, Wk, Wv, Wo, qA, kA, vA, pA,
                                          qB, kB, vB, pB, x_bf, Wqkv_b, Wo_b);

    // 2. qkv = x @ Weff_qkv^T, fused RoPE/pack epilogue
    gemm_tn<<<dim3(12, 64), 256, 0, stream>>>(x_bf, Wqkv_b, DIMc,
                                              2, nullptr, 0,
                                              q_gain, qatt, katt, vatt);

    // 3. attention
    flash_attn6<<<dim3(32, Bc * Hc), 256, 0, stream>>>(qatt, katt, vatt, head_gate, y_bf);

    // 4. out = y @ Weff_o^T (fp32)
    gemm_tn<<<dim3(8, 64), 256, 0, stream>>>(y_bf, Wo_b, DIMc,
                                             0, out, DIMc,
                                             nullptr, nullptr, nullptr, nullptr);
}

// Round 9
// 191.763 us; speedup vs baseline: 1.3096x; 1.3096x over previous
//
#include <hip/hip_runtime.h>
#include <hip/hip_fp16.h>

#define Bc   2
#define Tc   2048
#define DIMc 1024
#define Hc   16
#define KVHc 4
#define HDc  64
#define Mc   4096   // B*T

typedef unsigned short u16;
typedef __attribute__((ext_vector_type(8))) short short8;
typedef __attribute__((ext_vector_type(8))) __bf16 bf16x8;
typedef __attribute__((ext_vector_type(2))) __bf16 bf16x2;
typedef __attribute__((ext_vector_type(4))) float f32x4;
typedef __attribute__((ext_vector_type(4))) unsigned short u16x4;

typedef const __attribute__((address_space(1))) void* gas_t;
typedef __attribute__((address_space(3))) void* las_t;

#define L2E 1.4426950408889634f
#define L2B 0.41524101186092035f   // log2(10000)/32

__device__ inline float bf2f(u16 u) {
    unsigned int x = ((unsigned int)u) << 16;
    return __builtin_bit_cast(float, x);
}
__device__ inline u16 f2bf(float f) {  // RNE
    unsigned int x = __builtin_bit_cast(unsigned int, f);
    x += 0x7fffu + ((x >> 16) & 1u);
    return (u16)(x >> 16);
}
__device__ inline unsigned int pkbf(float a, float b) {
#if __has_builtin(__builtin_amdgcn_cvt_pk_bf16_f32)
    bf16x2 r = __builtin_amdgcn_cvt_pk_bf16_f32(a, b);
    return __builtin_bit_cast(unsigned int, r);
#else
    return (unsigned int)f2bf(a) | ((unsigned int)f2bf(b) << 16);
#endif
}
__device__ inline u16x4 pk4(float a, float b, float c, float d) {
    uint2 u; u.x = pkbf(a, b); u.y = pkbf(c, d);
    return __builtin_bit_cast(u16x4, u);
}
__device__ inline float fexp2(float x) {
#if __has_builtin(__builtin_amdgcn_exp2f)
    return __builtin_amdgcn_exp2f(x);
#else
    return exp2f(x);
#endif
}
__device__ inline bf16x8 ld8(const u16* p) {
    return __builtin_bit_cast(bf16x8, *(const short8*)p);
}
__device__ inline f32x4 mfma16(bf16x8 a, bf16x8 b, f32x4 c) {
    return __builtin_amdgcn_mfma_f32_16x16x32_bf16(a, b, c, 0, 0, 0);
}
__device__ inline void gl_lds16(const u16* g, u16* l) {
    __builtin_amdgcn_global_load_lds((gas_t)g, (las_t)l, 16, 0, 0);
}

// ---------------------------------------------------------------------------
// prep: blocks [0,4096) = x fp32->bf16 cast; [4096,4736) = LoRA product GEMM
// L[m,k] = sum_r B[r,m_seg] * A[k,r]  (m in 0..2559 over q/k/v/p segments,
// k in 0..1023; K=32, one MFMA pass). Tiles staged fp32->bf16 in-kernel,
// COALESCED (A tile is a contiguous 8 KB block; B tile is 64-float row runs).
// This replaces the round-7 per-block A-gather that was TA-transaction-bound.
// ---------------------------------------------------------------------------
__global__ __launch_bounds__(256) void prep_kernel(
    const float* __restrict__ x,
    const float* __restrict__ qA, const float* __restrict__ kA,
    const float* __restrict__ vA, const float* __restrict__ pA,
    const float* __restrict__ qB, const float* __restrict__ kB,
    const float* __restrict__ vB, const float* __restrict__ pB,
    u16* __restrict__ x_bf, float* __restrict__ L)
{
    __shared__ __align__(16) u16 Ns[64 * 40];   // BT tile [n_local][r]
    __shared__ __align__(16) u16 Ks[64 * 40];   // A  tile [k_local][r]
    const int bx = blockIdx.x;
    const int tid = threadIdx.x;

    if (bx < 4096) {                       // --- x fp32 -> bf16 ---
        const int i = bx * 256 + tid;
        float4 v = ((const float4*)x)[i];
        ((u16x4*)x_bf)[i] = pk4(v.x, v.y, v.z, v.w);
        return;
    }
    // --- LoRA GEMM: 640 blocks, 64m x 64k tiles ---
    const int lb = bx - 4096;
    const int mt = lb >> 4, kt = lb & 15;
    const int m0 = mt * 64, k0 = kt * 64;
    const float* Apt; const float* Bpt; int bdim, nnb;
    if (m0 < 1024)      { Apt = qA; Bpt = qB; bdim = 1024; nnb = m0; }
    else if (m0 < 1280) { Apt = kA; Bpt = kB; bdim = 256;  nnb = m0 - 1024; }
    else if (m0 < 1536) { Apt = vA; Bpt = vB; bdim = 256;  nnb = m0 - 1280; }
    else                { Apt = pA; Bpt = pB; bdim = 1024; nnb = m0 - 1536; }

    {   // stage A[k0:k0+64, 0:32] (contiguous 8 KB) -> Ks bf16
        const int row = tid >> 2, c0 = (tid & 3) * 8;
        const float4 f0 = *(const float4*)(Apt + (size_t)(k0 + row) * 32 + c0);
        const float4 f1 = *(const float4*)(Apt + (size_t)(k0 + row) * 32 + c0 + 4);
        *(u16x4*)&Ks[row * 40 + c0]     = pk4(f0.x, f0.y, f0.z, f0.w);
        *(u16x4*)&Ks[row * 40 + c0 + 4] = pk4(f1.x, f1.y, f1.z, f1.w);
    }
    {   // stage B[0:32, nnb:nnb+64] transposed -> Ns bf16 (64-float row runs)
        const int col = tid & 63;
        const int r0 = (tid >> 6) * 8;
        #pragma unroll
        for (int i = 0; i < 8; i++)
            Ns[col * 40 + r0 + i] = f2bf(Bpt[(size_t)(r0 + i) * bdim + nnb + col]);
    }
    __syncthreads();
    const int wave = tid >> 6, lane = tid & 63;
    const int quad = lane >> 4, l16 = lane & 15;
    const int wm = wave >> 1, wn = wave & 1;
    bf16x8 a0 = ld8(&Ns[(wm * 32 + l16) * 40 + quad * 8]);
    bf16x8 a1 = ld8(&Ns[(wm * 32 + 16 + l16) * 40 + quad * 8]);
    bf16x8 b0 = ld8(&Ks[(wn * 32 + l16) * 40 + quad * 8]);
    bf16x8 b1 = ld8(&Ks[(wn * 32 + 16 + l16) * 40 + quad * 8]);
    f32x4 c00 = {}, c01 = {}, c10 = {}, c11 = {};
    c00 = mfma16(a0, b0, c00);
    c01 = mfma16(a0, b1, c01);
    c10 = mfma16(a1, b0, c10);
    c11 = mfma16(a1, b1, c11);
    #pragma unroll
    for (int r = 0; r < 4; r++) {
        const size_t row_a = (size_t)(m0 + wm * 32 + quad * 4 + r) * 1024;
        const size_t row_b = (size_t)(m0 + wm * 32 + 16 + quad * 4 + r) * 1024;
        L[row_a + k0 + wn * 32 + l16]      = c00[r];
        L[row_a + k0 + wn * 32 + 16 + l16] = c01[r];
        L[row_b + k0 + wn * 32 + l16]      = c10[r];
        L[row_b + k0 + wn * 32 + 16 + l16] = c11[r];
    }
}

// ---------------------------------------------------------------------------
// quant: int6 RTN fake-quant per weight row + coalesced LoRA add from L.
// One block per row (2560). Weff = Wdeq + L, stored bf16.
// ---------------------------------------------------------------------------
__device__ inline float block_sum(float v, volatile float* red) {
    #pragma unroll
    for (int off = 32; off; off >>= 1) v += __shfl_xor(v, off);
    __syncthreads();
    if ((threadIdx.x & 63) == 0) red[threadIdx.x >> 6] = v;
    __syncthreads();
    return red[0] + red[1] + red[2] + red[3];
}
__device__ inline float block_max(float v, volatile float* red) {
    #pragma unroll
    for (int off = 32; off; off >>= 1) v = fmaxf(v, __shfl_xor(v, off));
    __syncthreads();
    if ((threadIdx.x & 63) == 0) red[threadIdx.x >> 6] = v;
    __syncthreads();
    return fmaxf(fmaxf(red[0], red[1]), fmaxf(red[2], red[3]));
}

__global__ __launch_bounds__(256) void quant_kernel(
    const float* __restrict__ Wq, const float* __restrict__ Wk,
    const float* __restrict__ Wv, const float* __restrict__ Wo,
    const float* __restrict__ L,
    u16* __restrict__ Wqkv_b, u16* __restrict__ Wo_b)
{
    __shared__ float red[4];
    const int rblk = blockIdx.x;
    const int tid = threadIdx.x;
    const float* src; u16* dst;
    if (rblk < 1024)      { src = Wq + (size_t)rblk * DIMc;          dst = Wqkv_b + (size_t)rblk * DIMc; }
    else if (rblk < 1280) { src = Wk + (size_t)(rblk - 1024) * DIMc; dst = Wqkv_b + (size_t)rblk * DIMc; }
    else if (rblk < 1536) { src = Wv + (size_t)(rblk - 1280) * DIMc; dst = Wqkv_b + (size_t)rblk * DIMc; }
    else                  { src = Wo + (size_t)(rblk - 1536) * DIMc; dst = Wo_b + (size_t)(rblk - 1536) * DIMc; }

    float4 fv = ((const float4*)src)[tid];
    float tv[4] = {fv.x, fv.y, fv.z, fv.w};
    float ps = tv[0] + tv[1] + tv[2] + tv[3];
    float pa = fmaxf(fmaxf(fabsf(tv[0]), fabsf(tv[1])),
                     fmaxf(fabsf(tv[2]), fabsf(tv[3])));
    const float sum  = block_sum(ps, red);
    const float amax = block_max(pa, red);
    const float mean = sum * (1.0f / 1024.0f);
    float psq = 0.f;
    #pragma unroll
    for (int j = 0; j < 4; j++) { float d = tv[j] - mean; psq += d * d; }
    const float var  = block_sum(psq, red) * (1.0f / 1024.0f);
    const float row_std    = fmaxf(sqrtf(var), 1e-8f);
    const float row_absmax = fmaxf(amax, 1.0f / 31.0f);
    const float s1 = fmaxf(fmaxf(row_std * 12.85f, row_absmax * (1.0f / 31.0f)) * (1.0f / 31.0f),
                           1.0f / 31.0f);
    const float s2 = fmaxf(row_absmax * (1.0f / 31.0f), 1.0f / 31.0f);
    float pe1 = 0.f, pe2 = 0.f;
    #pragma unroll
    for (int j = 0; j < 4; j++) {
        float q1 = fminf(fmaxf(rintf(tv[j] / s1), -31.f), 31.f);
        float q2 = fminf(fmaxf(rintf(tv[j] / s2), -31.f), 31.f);
        float d1 = q1 * s1 - tv[j], d2 = q2 * s2 - tv[j];
        pe1 += d1 * d1; pe2 += d2 * d2;
    }
    const float e1 = block_sum(pe1, red);
    const float e2 = block_sum(pe2, red);
    const float ss = (e1 < e2) ? s1 : s2;
    const float sh = __half2float(__float2half(ss));

    const float4 lv = ((const float4*)(L + (size_t)rblk * 1024))[tid];  // coalesced
    const float lr[4] = {lv.x, lv.y, lv.z, lv.w};
    u16x4 outv;
    #pragma unroll
    for (int j = 0; j < 4; j++) {
        float q = fminf(fmaxf(rintf(tv[j] / ss), -31.f), 31.f);
        outv[j] = f2bf(q * sh + lr[j]);
    }
    ((u16x4*)dst)[tid] = outv;
}

// ---------------------------------------------------------------------------
// gemm_tn: C[M,N] = A[M,K] @ B[N,K]^T. Tile 64M x 128N, 4 waves (wave =
// 32M x 64N, acc[2][4]). K=1024, BK=32. Double-buffered global_load_lds
// staging with double-XOR chunk swizzle on the global side.
// mode 0: fp32 store to Cf.
// mode 2: fused QKV epilogue — q cols (<1024): RoPE + gain*0.125*log2e ->
//   qatt (b,h,t,hd); k cols (1024..1279): RoPE -> katt (b,kvh,t,hd);
//   v cols (1280..1535): transpose -> vatt (b,kvh,hd,t).
// ---------------------------------------------------------------------------
__global__ __launch_bounds__(256) void gemm_tn(
    const u16* __restrict__ A, const u16* __restrict__ Bm, int K,
    int mode, float* __restrict__ Cf, int ldc,
    const float* __restrict__ q_gain,
    u16* __restrict__ qatt, u16* __restrict__ katt, u16* __restrict__ vatt)
{
    __shared__ __align__(16) u16 As[2][2048];   // 64 x 32
    __shared__ __align__(16) u16 Bs[2][4096];   // 128 x 32
    const int tid = threadIdx.x;
    const int wave = tid >> 6, lane = tid & 63;
    const int quad = lane >> 4, l16 = lane & 15;
    const int wm = wave >> 1, wn = wave & 1;
    const int tileM = blockIdx.y * 64, tileN = blockIdx.x * 128;

    const u16* Abase = A + (size_t)tileM * K;
    const u16* Bbase = Bm + (size_t)tileN * K;

    auto stage_it = [&](int k0, int buf) {
        {   // A: 256 chunks, 1/thread
            const int g = tid;
            const int r = g >> 2;
            const int cg = (g & 3) ^ (r & 3) ^ ((r >> 2) & 3);
            gl_lds16(Abase + (size_t)r * K + k0 + cg * 8, &As[buf][(size_t)g * 8]);
        }
        #pragma unroll
        for (int i = 0; i < 2; i++) {   // B: 512 chunks, 2/thread
            const int g = i * 256 + tid;
            const int r = g >> 2;
            const int cg = (g & 3) ^ (r & 3) ^ ((r >> 2) & 3);
            gl_lds16(Bbase + (size_t)r * K + k0 + cg * 8, &Bs[buf][(size_t)g * 8]);
        }
    };

    const int niter = K / 32;
    const int slot = quad ^ (l16 & 3) ^ ((l16 >> 2) & 3);
    f32x4 acc[2][4] = {};

    stage_it(0, 0);
    for (int it = 0; it < niter; it++) {
        const int buf = it & 1;
        __syncthreads();
        if (it + 1 < niter) stage_it((it + 1) * 32, buf ^ 1);
        bf16x8 af[2], bfr[4];
        #pragma unroll
        for (int mi = 0; mi < 2; mi++)
            af[mi] = ld8(&As[buf][(wm * 32 + mi * 16 + l16) * 32 + slot * 8]);
        #pragma unroll
        for (int ni = 0; ni < 4; ni++)
            bfr[ni] = ld8(&Bs[buf][(wn * 64 + ni * 16 + l16) * 32 + slot * 8]);
        #pragma unroll
        for (int mi = 0; mi < 2; mi++)
        #pragma unroll
        for (int ni = 0; ni < 4; ni++)
            acc[mi][ni] = mfma16(af[mi], bfr[ni], acc[mi][ni]);
    }

    const int row0 = tileM + wm * 32;
    const int col0 = tileN + wn * 64;
    if (mode == 0) {
        #pragma unroll
        for (int mi = 0; mi < 2; mi++)
        #pragma unroll
        for (int ni = 0; ni < 4; ni++)
        #pragma unroll
        for (int r = 0; r < 4; r++)
            Cf[(size_t)(row0 + mi * 16 + quad * 4 + r) * ldc + col0 + ni * 16 + l16]
                = acc[mi][ni][r];
        return;
    }
    // mode 2: fused qkv epilogue
    const int bb = row0 >> 11;
    const int trow = row0 & (Tc - 1);
    if (col0 < 1024) {                               // ---- q: RoPE, (t,hd) ----
        const int hh = col0 >> 6;
        const float g = q_gain[hh] * (0.125f * L2E);
        u16* qh = qatt + (size_t)(bb * Hc + hh) * Tc * HDc;
        #pragma unroll
        for (int ni = 0; ni < 2; ni++) {
            const int p = ni * 16 + l16;
            const float infr = fexp2(-L2B * (float)p);
            #pragma unroll
            for (int mi = 0; mi < 2; mi++) {
                #pragma unroll
                for (int r = 0; r < 4; r++) {
                    const int t = trow + mi * 16 + quad * 4 + r;
                    float s, c; __sincosf((float)t * infr, &s, &c);
                    const float x1 = acc[mi][ni][r], x2 = acc[mi][ni + 2][r];
                    qh[(size_t)t * HDc + p]      = f2bf((x1 * c + x2 * s) * g);
                    qh[(size_t)t * HDc + p + 32] = f2bf((x2 * c - x1 * s) * g);
                }
            }
        }
    } else if (col0 < 1280) {                        // ---- k: RoPE, (t,hd) ----
        const int kvh = (col0 - 1024) >> 6;
        u16* kh = katt + (size_t)(bb * KVHc + kvh) * Tc * HDc;
        #pragma unroll
        for (int ni = 0; ni < 2; ni++) {
            const int p = ni * 16 + l16;
            const float infr = fexp2(-L2B * (float)p);
            #pragma unroll
            for (int mi = 0; mi < 2; mi++) {
                #pragma unroll
                for (int r = 0; r < 4; r++) {
                    const int t = trow + mi * 16 + quad * 4 + r;
                    float s, c; __sincosf((float)t * infr, &s, &c);
                    const float x1 = acc[mi][ni][r], x2 = acc[mi][ni + 2][r];
                    kh[(size_t)t * HDc + p]      = f2bf(x1 * c + x2 * s);
                    kh[(size_t)t * HDc + p + 32] = f2bf(x2 * c - x1 * s);
                }
            }
        }
    } else {                                         // ---- v: (hd,t) ----
        const int kvh = (col0 - 1280) >> 6;
        u16* vh = vatt + (size_t)(bb * KVHc + kvh) * HDc * Tc;
        #pragma unroll
        for (int ni = 0; ni < 4; ni++) {
            const int hd = ni * 16 + l16;
            #pragma unroll
            for (int mi = 0; mi < 2; mi++) {
                const int t0 = trow + mi * 16 + quad * 4;
                u16x4 ov = pk4(acc[mi][ni][0], acc[mi][ni][1],
                               acc[mi][ni][2], acc[mi][ni][3]);
                *(u16x4*)(vh + (size_t)hd * Tc + t0) = ov;
            }
        }
    }
}

// ---------------------------------------------------------------------------
// Flash attention v6 (unchanged from round 7): balanced qtile schedule,
// no-max softmax (q pre-scaled by gain*0.125*log2e), HW exp2, packed bf16 cvt,
// K/V 64x64 tiles double-buffered via global_load_lds + XOR swizzle.
// ---------------------------------------------------------------------------
__global__ __launch_bounds__(256) void flash_attn6(
    const u16* __restrict__ qatt, const u16* __restrict__ katt,
    const u16* __restrict__ vatt, const float* __restrict__ head_gate,
    u16* __restrict__ ybf)
{
    __shared__ __align__(16) u16 sm[20480];   // [0,8192)=Kdbuf [8192,16384)=Vdbuf [16384,20480)=P
    const int tid = threadIdx.x;
    const int wv = tid >> 6, lane = tid & 63;
    const int quad = lane >> 4, l16 = lane & 15;
    const int sw = l16 & 7;
    const int bh = blockIdx.y;
    const int b = bh >> 4, h = bh & 15;
    const int kvh = h >> 2;
    const int x = blockIdx.x, s = bh >> 3;
    int qtile;
    if      (s == 0) qtile = x;
    else if (s == 1) qtile = 31 - x;
    else if (s == 2) qtile = (x + 8) & 31;
    else             qtile = 31 - ((x + 8) & 31);
    const int qw = qtile * 64 + wv * 16;
    const int nkt = qtile + 1;

    const u16* qbase = qatt + ((size_t)((b * Hc + h) * Tc + qw + l16)) * HDc;
    const bf16x8 bq0 = ld8(qbase + quad * 8);
    const bf16x8 bq1 = ld8(qbase + 32 + quad * 8);

    const u16* kbase = katt + (size_t)(b * KVHc + kvh) * Tc * HDc;
    const u16* vbase = vatt + (size_t)(b * KVHc + kvh) * HDc * Tc;

    auto stage = [&](int k0, int bb2) {
        #pragma unroll
        for (int i = 0; i < 2; i++) {
            const int g = wv * 128 + i * 64 + lane;
            const int r = g >> 3;
            const int cg = (g & 7) ^ (r & 7);
            gl_lds16(kbase + (size_t)(k0 + r) * HDc + cg * 8,
                     &sm[bb2 * 4096 + wv * 1024 + i * 512]);
            gl_lds16(vbase + (size_t)r * Tc + k0 + cg * 8,
                     &sm[8192 + bb2 * 4096 + wv * 1024 + i * 512]);
        }
    };

    float lsum = 0.f;
    f32x4 o[4] = {};
    u16* pw = &sm[16384 + wv * 1024];

    stage(0, 0);
    for (int kt = 0; kt < nkt; kt++) {
        const int bb2 = kt & 1;
        __syncthreads();
        if (kt + 1 < nkt) stage((kt + 1) * 64, bb2 ^ 1);

        const u16* Kb = &sm[bb2 * 4096];
        const u16* Vb = &sm[8192 + bb2 * 4096];
        f32x4 st[4];
        #pragma unroll
        for (int ft = 0; ft < 4; ft++) {
            const u16* kp = Kb + (ft * 16 + l16) * 64;
            bf16x8 a0 = ld8(kp + ((quad ^ sw) << 3));
            bf16x8 a1 = ld8(kp + (((quad + 4) ^ sw) << 3));
            f32x4 sacc = {};
            sacc = mfma16(a0, bq0, sacc);
            sacc = mfma16(a1, bq1, sacc);
            st[ft] = sacc;
        }
        if (kt == nkt - 1) {                 // diagonal: causal mask
            const int qloc = wv * 16 + l16;
            #pragma unroll
            for (int ft = 0; ft < 4; ft++)
                #pragma unroll
                for (int r = 0; r < 4; r++)
                    if (ft * 16 + quad * 4 + r > qloc) st[ft][r] = -1e30f;
        }
        #pragma unroll
        for (int ft = 0; ft < 4; ft++) {
            const float p0 = fexp2(st[ft][0]);
            const float p1 = fexp2(st[ft][1]);
            const float p2 = fexp2(st[ft][2]);
            const float p3 = fexp2(st[ft][3]);
            lsum += (p0 + p1) + (p2 + p3);
            const int c = (ft << 1) + (quad >> 1);
            u16* pd = &pw[(l16 << 6) + ((c ^ sw) << 3) + ((quad & 1) << 2)];
            uint2 pkv; pkv.x = pkbf(p0, p1); pkv.y = pkbf(p2, p3);
            *(uint2*)pd = pkv;
        }
        const bf16x8 pa0 = ld8(&pw[(l16 << 6) + ((quad ^ sw) << 3)]);
        const bf16x8 pa1 = ld8(&pw[(l16 << 6) + (((quad + 4) ^ sw) << 3)]);
        #pragma unroll
        for (int f = 0; f < 4; f++) {
            const u16* vp = Vb + (f * 16 + l16) * 64;
            bf16x8 v0 = ld8(vp + ((quad ^ sw) << 3));
            bf16x8 v1 = ld8(vp + (((quad + 4) ^ sw) << 3));
            o[f] = mfma16(v0, pa0, o[f]);
            o[f] = mfma16(v1, pa1, o[f]);
        }
    }
    lsum += __shfl_xor(lsum, 16);
    lsum += __shfl_xor(lsum, 32);
    const float inv = head_gate[h] / lsum;
    u16* yb = ybf + ((size_t)(b * Tc + qw + l16)) * DIMc + h * HDc + quad * 4;
    #pragma unroll
    for (int f = 0; f < 4; f++) {
        u16x4 pk = pk4(o[f][0] * inv, o[f][1] * inv,
                       o[f][2] * inv, o[f][3] * inv);
        *(u16x4*)(yb + f * 16) = pk;
    }
}

// ---------------------------------------------------------------------------
extern "C" void kernel_launch(void* const* d_in, const int* in_sizes, int n_in,
                              void* d_out, int out_size, void* d_ws, size_t ws_size,
                              hipStream_t stream) {
    (void)in_sizes; (void)n_in; (void)out_size; (void)ws_size;
    const float* x    = (const float*)d_in[0];
    const float* Wq   = (const float*)d_in[1];
    const float* Wk   = (const float*)d_in[2];
    const float* Wv   = (const float*)d_in[3];
    const float* Wo   = (const float*)d_in[4];
    const float* qA   = (const float*)d_in[5];
    const float* qB   = (const float*)d_in[6];
    const float* kA   = (const float*)d_in[7];
    const float* kB   = (const float*)d_in[8];
    const float* vA   = (const float*)d_in[9];
    const float* vB   = (const float*)d_in[10];
    const float* pA   = (const float*)d_in[11];
    const float* pB   = (const float*)d_in[12];
    const float* q_gain    = (const float*)d_in[13];
    const float* head_gate = (const float*)d_in[14];
    float* out = (float*)d_out;

    char* wsp = (char*)d_ws;
    size_t off = 0;
    auto alloc = [&](size_t bytes) -> void* {
        void* p = wsp + off;
        off = (off + bytes + 255) & ~(size_t)255;
        return p;
    };
    u16* x_bf    = (u16*)alloc((size_t)Mc * DIMc * 2);
    float* Lbuf  = (float*)alloc((size_t)2560 * 1024 * 4);   // LoRA products
    u16* Wqkv_b  = (u16*)alloc((size_t)1536 * DIMc * 2);     // LoRA-folded Weff
    u16* Wo_b    = (u16*)alloc((size_t)DIMc * DIMc * 2);     // LoRA-folded Weff
    u16* qatt    = (u16*)alloc((size_t)Mc * DIMc * 2);
    u16* katt    = (u16*)alloc((size_t)Mc * 256 * 2);
    u16* vatt    = (u16*)alloc((size_t)Mc * 256 * 2);
    u16* y_bf    = (u16*)alloc((size_t)Mc * DIMc * 2);

    // 1. x cast + LoRA product GEMM (independent block ranges)
    prep_kernel<<<4736, 256, 0, stream>>>(x, qA, kA, vA, pA, qB, kB, vB, pB,
                                          x_bf, Lbuf);

    // 2. quant + fold (coalesced L read)
    quant_kernel<<<2560, 256, 0, stream>>>(Wq, Wk, Wv, Wo, Lbuf, Wqkv_b, Wo_b);

    // 3. qkv = x @ Weff_qkv^T, fused RoPE/pack epilogue
    gemm_tn<<<dim3(12, 64), 256, 0, stream>>>(x_bf, Wqkv_b, DIMc,
                                              2, nullptr, 0,
                                              q_gain, qatt, katt, vatt);

    // 4. attention
    flash_attn6<<<dim3(32, Bc * Hc), 256, 0, stream>>>(qatt, katt, vatt, head_gate, y_bf);

    // 5. out = y @ Weff_o^T (fp32)
    gemm_tn<<<dim3(8, 64), 256, 0, stream>>>(y_bf, Wo_b, DIMc,
                                             0, out, DIMc,
                                             nullptr, nullptr, nullptr, nullptr);
}